// Round 9
// baseline (324.769 us; speedup 1.0000x reference)
//
#include <hip/hip_runtime.h>

typedef __attribute__((ext_vector_type(4))) float  f32x4;
typedef __attribute__((ext_vector_type(4))) float  float4v;
typedef __attribute__((ext_vector_type(8))) short  short8;
typedef __attribute__((ext_vector_type(4))) short  short4v;

#define TQ 1500
#define TP 1536
#define CC 1024
#define EPS 1e-6f

// ---------------- workspace layout (bytes) ----------------
#define XT_OFF    ((size_t)0)          // (B,TP,CC) bf16 (flat 12288 x 1024)
#define XAT_OFF   ((size_t)25165824)   // (B,TP,CC) bf16
#define OUT_OFF   ((size_t)50331648)   // (B,TP,CC) bf16 (outT)
#define WB_OFF    ((size_t)75497472)   // 4x (CC,CC) bf16
#define KSUM_OFF  ((size_t)83886080)   // (B,CC) f32
#define KVSUM_OFF ((size_t)83918848)   // (B,CC) f32

#define VMCNT4() asm volatile("s_waitcnt vmcnt(4)" ::: "memory")
#define VMCNT0() asm volatile("s_waitcnt vmcnt(0)" ::: "memory")
#define LGKM0()  asm volatile("s_waitcnt lgkmcnt(0)" ::: "memory")
#define SBAR()   __builtin_amdgcn_s_barrier()
#define SCHED0() __builtin_amdgcn_sched_barrier(0)

__device__ __forceinline__ float bf2f(short s) {
    union { unsigned u; float f; } v; v.u = ((unsigned)(unsigned short)s) << 16; return v.f;
}
__device__ __forceinline__ short f2bf(float f) {
    union { float f; unsigned u; } v; v.f = f;
    unsigned r = (v.u + 0x7FFFu + ((v.u >> 16) & 1u)) >> 16;
    return (short)r;
}
__device__ __forceinline__ float phi_f(float x) {
    return x / (1.f + __expf(-x)) + 1.f;   // silu(x)+1
}
__device__ __forceinline__ void gl_lds16(const void* g, void* l) {
    __builtin_amdgcn_global_load_lds((const __attribute__((address_space(1))) void*)g,
                                     (__attribute__((address_space(3))) void*)l, 16, 0, 0);
}

// LDS chunk swizzle (measured 0 conflicts r5/r8): physical slot p holds global
// chunk p ^ ((row>>1)&3); rows advance by multiples of 16 everywhere so the
// XOR is a per-lane constant on both stage and read sides.

// ---------------- weight cast fp32 -> bf16 ----------------
__global__ __launch_bounds__(256)
void conv_w_kernel(const float* __restrict__ w0, const float* __restrict__ w1,
                   const float* __restrict__ w2, const float* __restrict__ w3,
                   short* __restrict__ o0, short* __restrict__ o1,
                   short* __restrict__ o2, short* __restrict__ o3)
{
    const int i = (blockIdx.x * 256 + threadIdx.x) * 4;
    float4v a = *(const float4v*)(w0 + i);
    float4v b = *(const float4v*)(w1 + i);
    float4v c = *(const float4v*)(w2 + i);
    float4v d = *(const float4v*)(w3 + i);
    short4v ra, rb, rc, rd;
#pragma unroll
    for (int j = 0; j < 4; ++j) {
        ra[j] = f2bf(a[j]); rb[j] = f2bf(b[j]); rc[j] = f2bf(c[j]); rd[j] = f2bf(d[j]);
    }
    *(short4v*)(o0 + i) = ra;
    *(short4v*)(o1 + i) = rb;
    *(short4v*)(o2 + i) = rc;
    *(short4v*)(o3 + i) = rd;
}

// ------- transpose-cast (B,C,T)fp32 -> (B,TP,C)bf16, zero-pad t>=TQ; x and xa merged -------
__global__ __launch_bounds__(256)
void xpose_kernel(const float* __restrict__ x, const float* __restrict__ xa,
                  short* __restrict__ xT, short* __restrict__ xaT)
{
    __shared__ float tile[64][65];
    const int z  = blockIdx.z;
    const int b  = z & 7;
    const float* src = (z < 8) ? x : xa;
    short* dst       = (z < 8) ? xT : xaT;
    const int c0 = blockIdx.y * 64;
    const int t0 = blockIdx.x * 64;
    const int tl = threadIdx.x & 63;
    const int q  = threadIdx.x >> 6;
    const int t  = t0 + tl;
#pragma unroll
    for (int i = 0; i < 16; ++i) {
        const int cl = q * 16 + i;
        float v = 0.f;
        if (t < TQ) v = src[((size_t)b * CC + c0 + cl) * TQ + t];
        tile[cl][tl] = v;
    }
    __syncthreads();
#pragma unroll
    for (int i = 0; i < 16; ++i) {
        const int t2 = q * 16 + i;
        dst[((size_t)b * TP + t0 + t2) * CC + c0 + tl] = f2bf(tile[tl][t2]);
    }
}

// =====================================================================
// Pipelined GEMM skeleton v2: 256 thr (4 waves, 2M x 2N), per-wave 64x64
// (4x4 frags: 8 ds_read_b128 -> 16 MFMA, 0.5 reads/MFMA), BM=BN=128,
// BK=32, TRIPLE-buffered LDS (16KB/buf, 48KB total -> 3 blocks/CU),
// stage-ahead 2, counted vmcnt(4), 1 s_barrier / K-tile.
// Staging: thread covers chunks {wave*128+lane, +64}: rows wave*32+(lane>>2)
// and +16; swizzled col = ((lane&3)^(((lane>>2)>>1)&3))*8, lane-constant.
// =====================================================================

// ------- gemm_q_out : pq = phi(Wq x + bq); den-reduce; outT = pq*kvsum*0.125/(den+eps) -------
// grid 768 = 96 mrow x 8 nt; XCD-swizzled, nt fastest
__global__ __launch_bounds__(256, 4)
void gemm_q_out_kernel(const short* __restrict__ xT, const short* __restrict__ Wqb,
                       const float* __restrict__ bq, const float* __restrict__ ksum,
                       const float* __restrict__ kvsum, short* __restrict__ outT)
{
    __shared__ short lds[3][8192];   // [buf][A 4096 | B 4096]
    const int f    = blockIdx.x;
    const int L    = (f & 7) * 96 + (f >> 3);
    const int nt   = L % 8;
    const int mrow = L / 8;          // 0..95
    const int b    = mrow / 12;
    const int tid  = threadIdx.x;
    const int wave = tid >> 6, lane = tid & 63;
    const int wr = wave >> 1;        // 0..1 : m 64-span
    const int wc = wave & 1;         // 0..1 : n 64-span
    const int rl = lane & 15;
    const int q4 = lane >> 4;
    const int rg = (q4 ^ ((rl >> 1) & 3)) << 3;

    // staging
    const int lrow = lane >> 2;
    const int kc   = ((lane & 3) ^ ((lrow >> 1) & 3)) << 3;
    const int row0 = wave * 32 + lrow;
    const short* aP0 = xT  + (size_t)(mrow * 128 + row0) * CC + kc;
    const short* aP1 = aP0 + 16 * CC;
    const short* bP0 = Wqb + (size_t)(nt * 128 + row0) * CC + kc;
    const short* bP1 = bP0 + 16 * CC;
    const int aD0 = wave * 1024, aD1 = aD0 + 512;
    const int bD0 = 4096 + aD0,  bD1 = bD0 + 512;

    const int aoff0 = (wr * 64 + rl) * 32 + rg;
    const int boff0 = 4096 + (wc * 64 + rl) * 32 + rg;

    f32x4 acc[4][4] = {};

    // prologue: stage bufs 0,1
#pragma unroll
    for (int s = 0; s < 2; ++s) {
        gl_lds16(aP0, &lds[s][aD0]); gl_lds16(aP1, &lds[s][aD1]);
        gl_lds16(bP0, &lds[s][bD0]); gl_lds16(bP1, &lds[s][bD1]);
        aP0 += 32; aP1 += 32; bP0 += 32; bP1 += 32;
    }
    VMCNT4(); SBAR();

    int cur = 0;
#pragma unroll 1
    for (int kt = 0; kt < 32; ++kt) {
        if (kt <= 29) {
            const int pn = (cur == 0) ? 2 : cur - 1;   // (kt+2)%3
            gl_lds16(aP0, &lds[pn][aD0]); gl_lds16(aP1, &lds[pn][aD1]);
            gl_lds16(bP0, &lds[pn][bD0]); gl_lds16(bP1, &lds[pn][bD1]);
            aP0 += 32; aP1 += 32; bP0 += 32; bP1 += 32;
        }
        short8 ra[4], rb[4];
#pragma unroll
        for (int i = 0; i < 4; ++i) {
            ra[i] = *(const short8*)&lds[cur][aoff0 + i * 512];
            rb[i] = *(const short8*)&lds[cur][boff0 + i * 512];
        }
        LGKM0(); SCHED0();
        __builtin_amdgcn_s_setprio(1);
#pragma unroll
        for (int i = 0; i < 4; ++i)
#pragma unroll
            for (int j = 0; j < 4; ++j)
                acc[i][j] = __builtin_amdgcn_mfma_f32_16x16x32_bf16(ra[i], rb[j], acc[i][j], 0, 0, 0);
        __builtin_amdgcn_s_setprio(0);
        if (kt <= 29)      { VMCNT4(); }
        else if (kt == 30) { VMCNT0(); }
        if (kt < 31) SBAR();
        cur = (cur == 2) ? 0 : cur + 1;
    }

    // ---- fused epilogue: wave wc's 64-col span = one full head ----
    float bias[4], ks[4], kv[4];
#pragma unroll
    for (int j = 0; j < 4; ++j) {
        const int c = nt * 128 + wc * 64 + j * 16 + rl;
        bias[j] = bq[c];
        ks[j]   = ksum[b * CC + c];
        kv[j]   = kvsum[b * CC + c];
    }
#pragma unroll
    for (int i = 0; i < 4; ++i)
#pragma unroll
        for (int j = 0; j < 4; ++j)
#pragma unroll
            for (int r = 0; r < 4; ++r)
                acc[i][j][r] = phi_f(acc[i][j][r] + bias[j]);
#pragma unroll
    for (int i = 0; i < 4; ++i) {
#pragma unroll
        for (int r = 0; r < 4; ++r) {
            float d = acc[i][0][r] * ks[0] + acc[i][1][r] * ks[1]
                    + acc[i][2][r] * ks[2] + acc[i][3][r] * ks[3];
            d += __shfl_xor(d, 1); d += __shfl_xor(d, 2);
            d += __shfl_xor(d, 4); d += __shfl_xor(d, 8);
            const float inv = 0.125f / (d + EPS);
            const int trow = mrow * 128 + wr * 64 + i * 16 + q4 * 4 + r;
#pragma unroll
            for (int j = 0; j < 4; ++j) {
                const int c = nt * 128 + wc * 64 + j * 16 + rl;
                outT[(size_t)trow * CC + c] = f2bf(acc[i][j][r] * kv[j] * inv);
            }
        }
    }
}

// ------- gemm_kv : dual GEMM (k,v) fused phi + t-reduction -> ksum/kvsum -------
// grid 1536 = 96 mrow x 16 cb; B-LDS rows 0-63 = Wk, 64-127 = Wv (waves 0,1 stage k; 2,3 stage v)
__global__ __launch_bounds__(256, 4)
void gemm_kv_kernel(const short* __restrict__ xaT, const short* __restrict__ Wkb,
                    const short* __restrict__ Wvb, const float* __restrict__ bv,
                    float* __restrict__ ksum, float* __restrict__ kvsum)
{
    __shared__ short lds[3][8192];
    const int f    = blockIdx.x;
    const int L    = (f & 7) * 192 + (f >> 3);
    const int cb   = L % 16;
    const int mrow = L / 16;         // 0..95
    const int b    = mrow / 12;
    const int tid  = threadIdx.x;
    const int wave = tid >> 6, lane = tid & 63;
    const int wr = wave >> 1;
    const int wc = wave & 1;         // 0..1 : c 32-span
    const int rl = lane & 15;
    const int q4 = lane >> 4;
    const int rg = (q4 ^ ((rl >> 1) & 3)) << 3;

    const int lrow = lane >> 2;
    const int kc   = ((lane & 3) ^ ((lrow >> 1) & 3)) << 3;
    const int row0 = wave * 32 + lrow;              // A row; B row (k rows 0-63, v rows 64-127)
    const short* aP0 = xaT + (size_t)(mrow * 128 + row0) * CC + kc;
    const short* aP1 = aP0 + 16 * CC;
    const short* bPanel = (wave < 2)
        ? Wkb + (size_t)cb * 64 * CC
        : Wvb + (size_t)cb * 64 * CC - (size_t)64 * CC;
    const short* bP0 = bPanel + (size_t)row0 * CC + kc;
    const short* bP1 = bP0 + 16 * CC;
    const int aD0 = wave * 1024, aD1 = aD0 + 512;
    const int bD0 = 4096 + aD0,  bD1 = bD0 + 512;

    const int aoff0 = (wr * 64 + rl) * 32 + rg;
    const int boffK = 4096 + (wc * 32 + rl) * 32 + rg;   // + jj*512
    const int boffV = boffK + 2048;

    f32x4 acc[4][4] = {};   // [i][0..1]=k, [i][2..3]=v (same cols)

#pragma unroll
    for (int s = 0; s < 2; ++s) {
        gl_lds16(aP0, &lds[s][aD0]); gl_lds16(aP1, &lds[s][aD1]);
        gl_lds16(bP0, &lds[s][bD0]); gl_lds16(bP1, &lds[s][bD1]);
        aP0 += 32; aP1 += 32; bP0 += 32; bP1 += 32;
    }
    VMCNT4(); SBAR();

    int cur = 0;
#pragma unroll 1
    for (int kt = 0; kt < 32; ++kt) {
        if (kt <= 29) {
            const int pn = (cur == 0) ? 2 : cur - 1;
            gl_lds16(aP0, &lds[pn][aD0]); gl_lds16(aP1, &lds[pn][aD1]);
            gl_lds16(bP0, &lds[pn][bD0]); gl_lds16(bP1, &lds[pn][bD1]);
            aP0 += 32; aP1 += 32; bP0 += 32; bP1 += 32;
        }
        short8 ra[4], rb[4];
#pragma unroll
        for (int i = 0; i < 4; ++i)
            ra[i] = *(const short8*)&lds[cur][aoff0 + i * 512];
#pragma unroll
        for (int j = 0; j < 2; ++j) {
            rb[j]     = *(const short8*)&lds[cur][boffK + j * 512];
            rb[j + 2] = *(const short8*)&lds[cur][boffV + j * 512];
        }
        LGKM0(); SCHED0();
        __builtin_amdgcn_s_setprio(1);
#pragma unroll
        for (int i = 0; i < 4; ++i)
#pragma unroll
            for (int j = 0; j < 4; ++j)
                acc[i][j] = __builtin_amdgcn_mfma_f32_16x16x32_bf16(ra[i], rb[j], acc[i][j], 0, 0, 0);
        __builtin_amdgcn_s_setprio(0);
        if (kt <= 29)      { VMCNT4(); }
        else if (kt == 30) { VMCNT0(); }
        if (kt < 31) SBAR();
        cur = (cur == 2) ? 0 : cur + 1;
    }

    const int tq0 = (mrow % 12) * 128 + wr * 64 + q4 * 4;
#pragma unroll
    for (int jj = 0; jj < 2; ++jj) {
        const int c = cb * 64 + wc * 32 + jj * 16 + rl;
        const float bvc = bv[c];
        float sk = 0.f, skv = 0.f;
#pragma unroll
        for (int i = 0; i < 4; ++i) {
#pragma unroll
            for (int r = 0; r < 4; ++r) {
                if (tq0 + i * 16 + r < TQ) {
                    float pk = phi_f(acc[i][jj][r]);
                    float vv = acc[i][jj + 2][r] + bvc;
                    sk  += pk;
                    skv += pk * vv;
                }
            }
        }
        sk  += __shfl_xor(sk, 16);  sk  += __shfl_xor(sk, 32);
        skv += __shfl_xor(skv, 16); skv += __shfl_xor(skv, 32);
        if (q4 == 0) {
            atomicAdd(&ksum[b * CC + c], sk);
            atomicAdd(&kvsum[b * CC + c], skv);
        }
    }
}

// ---------------- gemm_o : y[b][c][t] = Wo out + bo, m=c n=t, mask t<TQ ----------------
// grid 768 = (8 b x 12 tt) x 8 ct; XCD-swizzled, ct fastest
__global__ __launch_bounds__(256, 4)
void gemm_o_kernel(const short* __restrict__ Wob, const short* __restrict__ outT,
                   const float* __restrict__ bo, float* __restrict__ y)
{
    __shared__ short lds[3][8192];
    const int f    = blockIdx.x;
    const int L    = (f & 7) * 96 + (f >> 3);
    const int ct   = L % 8;
    const int rest = L / 8;          // 0..95 = b*12 + tt
    const int b    = rest / 12;
    const int tt   = rest % 12;
    const int tid  = threadIdx.x;
    const int wave = tid >> 6, lane = tid & 63;
    const int wr = wave >> 1;        // m = c 64-span
    const int wc = wave & 1;         // n = t 64-span
    const int rl = lane & 15;
    const int q4 = lane >> 4;
    const int rg = (q4 ^ ((rl >> 1) & 3)) << 3;

    const int lrow = lane >> 2;
    const int kc   = ((lane & 3) ^ ((lrow >> 1) & 3)) << 3;
    const int row0 = wave * 32 + lrow;
    const short* aP0 = Wob  + (size_t)(ct * 128 + row0) * CC + kc;
    const short* aP1 = aP0 + 16 * CC;
    const short* bP0 = outT + (size_t)(rest * 128 + row0) * CC + kc;
    const short* bP1 = bP0 + 16 * CC;
    const int aD0 = wave * 1024, aD1 = aD0 + 512;
    const int bD0 = 4096 + aD0,  bD1 = bD0 + 512;

    const int aoff0 = (wr * 64 + rl) * 32 + rg;
    const int boff0 = 4096 + (wc * 64 + rl) * 32 + rg;

    f32x4 acc[4][4] = {};

#pragma unroll
    for (int s = 0; s < 2; ++s) {
        gl_lds16(aP0, &lds[s][aD0]); gl_lds16(aP1, &lds[s][aD1]);
        gl_lds16(bP0, &lds[s][bD0]); gl_lds16(bP1, &lds[s][bD1]);
        aP0 += 32; aP1 += 32; bP0 += 32; bP1 += 32;
    }
    VMCNT4(); SBAR();

    int cur = 0;
#pragma unroll 1
    for (int kt = 0; kt < 32; ++kt) {
        if (kt <= 29) {
            const int pn = (cur == 0) ? 2 : cur - 1;
            gl_lds16(aP0, &lds[pn][aD0]); gl_lds16(aP1, &lds[pn][aD1]);
            gl_lds16(bP0, &lds[pn][bD0]); gl_lds16(bP1, &lds[pn][bD1]);
            aP0 += 32; aP1 += 32; bP0 += 32; bP1 += 32;
        }
        short8 ra[4], rb[4];
#pragma unroll
        for (int i = 0; i < 4; ++i) {
            ra[i] = *(const short8*)&lds[cur][aoff0 + i * 512];
            rb[i] = *(const short8*)&lds[cur][boff0 + i * 512];
        }
        LGKM0(); SCHED0();
        __builtin_amdgcn_s_setprio(1);
#pragma unroll
        for (int i = 0; i < 4; ++i)
#pragma unroll
            for (int j = 0; j < 4; ++j)
                acc[i][j] = __builtin_amdgcn_mfma_f32_16x16x32_bf16(ra[i], rb[j], acc[i][j], 0, 0, 0);
        __builtin_amdgcn_s_setprio(0);
        if (kt <= 29)      { VMCNT4(); }
        else if (kt == 30) { VMCNT0(); }
        if (kt < 31) SBAR();
        cur = (cur == 2) ? 0 : cur + 1;
    }

#pragma unroll
    for (int j = 0; j < 4; ++j) {
        const int t = tt * 128 + wc * 64 + j * 16 + rl;
        if (t >= TQ) continue;
#pragma unroll
        for (int i = 0; i < 4; ++i) {
            const int cbase = ct * 128 + wr * 64 + i * 16 + q4 * 4;
#pragma unroll
            for (int r = 0; r < 4; ++r) {
                const int c = cbase + r;
                y[((size_t)b * CC + c) * TQ + t] = acc[i][j][r] + bo[c];
            }
        }
    }
}

extern "C" void kernel_launch(void* const* d_in, const int* in_sizes, int n_in,
                              void* d_out, int out_size, void* d_ws, size_t ws_size,
                              hipStream_t stream)
{
    (void)in_sizes; (void)n_in; (void)out_size; (void)ws_size;
    const float* x  = (const float*)d_in[0];
    const float* xa = (const float*)d_in[1];
    const float* Wq = (const float*)d_in[2];
    const float* bq = (const float*)d_in[3];
    const float* Wk = (const float*)d_in[4];
    const float* Wv = (const float*)d_in[5];
    const float* bv = (const float*)d_in[6];
    const float* Wo = (const float*)d_in[7];
    const float* bo = (const float*)d_in[8];
    float* y = (float*)d_out;
    char* ws = (char*)d_ws;

    short* xT    = (short*)(ws + XT_OFF);
    short* xaT   = (short*)(ws + XAT_OFF);
    short* outT  = (short*)(ws + OUT_OFF);
    short* Wqb   = (short*)(ws + WB_OFF);
    short* Wkb   = Wqb + (size_t)CC * CC;
    short* Wvb   = Wkb + (size_t)CC * CC;
    short* Wob   = Wvb + (size_t)CC * CC;
    float* ksum  = (float*)(ws + KSUM_OFF);
    float* kvsum = (float*)(ws + KVSUM_OFF);

    conv_w_kernel<<<dim3(CC * CC / 4 / 256), 256, 0, stream>>>(Wq, Wk, Wv, Wo, Wqb, Wkb, Wvb, Wob);
    xpose_kernel<<<dim3(TP / 64, CC / 64, 16), 256, 0, stream>>>(x, xa, xT, xaT);
    hipMemsetAsync(ws + KSUM_OFF, 0, 65536, stream);

    gemm_kv_kernel<<<dim3(1536), 256, 0, stream>>>(xaT, Wkb, Wvb, bv, ksum, kvsum);
    gemm_q_out_kernel<<<dim3(768), 256, 0, stream>>>(xT, Wqb, bq, ksum, kvsum, outT);
    gemm_o_kernel<<<dim3(768), 256, 0, stream>>>(Wob, outT, bo, y);
}

// Round 11
// 311.170 us; speedup vs baseline: 1.0437x; 1.0437x over previous
//
#include <hip/hip_runtime.h>

typedef __attribute__((ext_vector_type(4))) float  f32x4;
typedef __attribute__((ext_vector_type(4))) float  float4v;
typedef __attribute__((ext_vector_type(8))) short  short8;
typedef __attribute__((ext_vector_type(4))) short  short4v;

#define TQ 1500
#define TP 1536
#define CC 1024
#define EPS 1e-6f

// ---------------- workspace layout (bytes) ----------------
#define XT_OFF    ((size_t)0)          // (B,TP,CC) bf16 (flat 12288 x 1024)
#define XAT_OFF   ((size_t)25165824)   // (B,TP,CC) bf16
#define OUT_OFF   ((size_t)50331648)   // (B,TP,CC) bf16 (outT)
#define WB_OFF    ((size_t)75497472)   // 4x (CC,CC) bf16
#define KSUM_OFF  ((size_t)83886080)   // (B,CC) f32  (ksum+kvsum = 64KB, zeroed in prep)
#define KVSUM_OFF ((size_t)83918848)   // (B,CC) f32

#define VMCNT8() asm volatile("s_waitcnt vmcnt(8)" ::: "memory")
#define VMCNT4() asm volatile("s_waitcnt vmcnt(4)" ::: "memory")
#define VMCNT0() asm volatile("s_waitcnt vmcnt(0)" ::: "memory")
#define SBAR()   __builtin_amdgcn_s_barrier()
#define SCHED0() __builtin_amdgcn_sched_barrier(0)

__device__ __forceinline__ float bf2f(short s) {
    union { unsigned u; float f; } v; v.u = ((unsigned)(unsigned short)s) << 16; return v.f;
}
__device__ __forceinline__ short f2bf(float f) {
    union { float f; unsigned u; } v; v.f = f;
    unsigned r = (v.u + 0x7FFFu + ((v.u >> 16) & 1u)) >> 16;
    return (short)r;
}
__device__ __forceinline__ float phi_f(float x) {
    return x / (1.f + __expf(-x)) + 1.f;   // silu(x)+1
}
__device__ __forceinline__ void gl_lds16(const void* g, void* l) {
    __builtin_amdgcn_global_load_lds((const __attribute__((address_space(1))) void*)g,
                                     (__attribute__((address_space(3))) void*)l, 16, 0, 0);
}

// LDS chunk swizzle (measured 0 conflicts r5/r8/r9): physical slot p holds
// global chunk p ^ ((row>>1)&3); rows advance by multiples of 16 on both the
// stage and read sides so the XOR is a per-lane constant.

// ---------------- prep: weight cast + ksum zero + transpose-cast, one dispatch ----------------
__global__ __launch_bounds__(256)
void prep_kernel(const float* __restrict__ x, const float* __restrict__ xa,
                 const float* __restrict__ w0, const float* __restrict__ w1,
                 const float* __restrict__ w2, const float* __restrict__ w3,
                 short* __restrict__ o0, short* __restrict__ o1,
                 short* __restrict__ o2, short* __restrict__ o3,
                 short* __restrict__ xT, short* __restrict__ xaT,
                 float* __restrict__ zbuf)
{
    __shared__ float tile[64][65];
    const int bid = blockIdx.x;
    const int tid = threadIdx.x;
    if (bid < 1024) {
        // weight cast fp32->bf16 (4 matrices)
        const int i = (bid * 256 + tid) * 4;
        float4v a = *(const float4v*)(w0 + i);
        float4v b = *(const float4v*)(w1 + i);
        float4v c = *(const float4v*)(w2 + i);
        float4v d = *(const float4v*)(w3 + i);
        short4v ra, rb, rc, rd;
#pragma unroll
        for (int j = 0; j < 4; ++j) {
            ra[j] = f2bf(a[j]); rb[j] = f2bf(b[j]); rc[j] = f2bf(c[j]); rd[j] = f2bf(d[j]);
        }
        *(short4v*)(o0 + i) = ra;
        *(short4v*)(o1 + i) = rb;
        *(short4v*)(o2 + i) = rc;
        *(short4v*)(o3 + i) = rd;
        // zero ksum/kvsum (16384 floats) with blocks 0..15
        if (bid < 16) {
            const int zb = bid * 1024 + tid;
            zbuf[zb] = 0.f; zbuf[zb + 256] = 0.f; zbuf[zb + 512] = 0.f; zbuf[zb + 768] = 0.f;
        }
    } else {
        // transpose-cast (B,C,T)fp32 -> (B,TP,C)bf16, zero-pad t>=TQ
        const int idx = bid - 1024;
        const int t0 = (idx % 24) * 64;
        const int c0 = ((idx / 24) % 16) * 64;
        const int z  = idx / 384;
        const int b  = z & 7;
        const float* src = (z < 8) ? x : xa;
        short* dst       = (z < 8) ? xT : xaT;
        const int tl = tid & 63;
        const int q  = tid >> 6;
        const int t  = t0 + tl;
#pragma unroll
        for (int i = 0; i < 16; ++i) {
            const int cl = q * 16 + i;
            float v = 0.f;
            if (t < TQ) v = src[((size_t)b * CC + c0 + cl) * TQ + t];
            tile[cl][tl] = v;
        }
        __syncthreads();
#pragma unroll
        for (int i = 0; i < 16; ++i) {
            const int t2 = q * 16 + i;
            dst[((size_t)b * TP + t0 + t2) * CC + c0 + tl] = f2bf(tile[tl][t2]);
        }
    }
}

// =====================================================================
// Pipelined GEMM skeleton v3: 256 thr (4 waves, 2M x 2N), per-wave 64x64,
// BM=BN=128, BK=32, QUAD-buffered LDS (16KB/buf, 64KB), stage-ahead 3,
// REGISTER double-buffered fragments: each half-step issues ds_reads for
// frags[k+1] + stage[k+3] BEFORE the MFMA cluster on frags[k] (compiler
// emits counted lgkmcnt -> read latency drains under MFMA). vmcnt(4) at
// every half-top retires exactly stage[k+1]; vmcnt(0) only at k=30.
// =====================================================================

#define GEMM_PROLOGUE()                                                         \
    for (int s = 0; s < 3; ++s) {                                               \
        gl_lds16(aP0, &lds[s][aD0]); gl_lds16(aP1, &lds[s][aD1]);               \
        gl_lds16(bP0, &lds[s][bD0]); gl_lds16(bP1, &lds[s][bD1]);               \
        aP0 += 32; aP1 += 32; bP0 += 32; bP1 += 32;                             \
    }                                                                           \
    VMCNT8(); SBAR();

#define STAGE_NEXT(buf)                                                         \
    { short* lb = &lds[buf][0];                                                 \
      gl_lds16(aP0, lb + aD0); gl_lds16(aP1, lb + aD1);                         \
      gl_lds16(bP0, lb + bD0); gl_lds16(bP1, lb + bD1);                         \
      aP0 += 32; aP1 += 32; bP0 += 32; bP1 += 32; }

// ------- gemm_q_out : pq = phi(Wq x + bq); den-reduce; outT = pq*kvsum*0.125/(den+eps) -------
// grid 768 = 96 mrow x 8 nt; XCD-swizzled, nt fastest
__global__ __launch_bounds__(256, 2)
void gemm_q_out_kernel(const short* __restrict__ xT, const short* __restrict__ Wqb,
                       const float* __restrict__ bq, const float* __restrict__ ksum,
                       const float* __restrict__ kvsum, short* __restrict__ outT)
{
    __shared__ short lds[4][8192];   // [buf][A 4096 | B 4096]
    const int f    = blockIdx.x;
    const int L    = (f & 7) * 96 + (f >> 3);
    const int nt   = L % 8;
    const int mrow = L / 8;
    const int b    = mrow / 12;
    const int tid  = threadIdx.x;
    const int wave = tid >> 6, lane = tid & 63;
    const int wr = wave >> 1;
    const int wc = wave & 1;
    const int rl = lane & 15;
    const int q4 = lane >> 4;
    const int rg = (q4 ^ ((rl >> 1) & 3)) << 3;

    const int lrow = lane >> 2;
    const int kc   = ((lane & 3) ^ ((lrow >> 1) & 3)) << 3;
    const int row0 = wave * 32 + lrow;
    const short* aP0 = xT  + (size_t)(mrow * 128 + row0) * CC + kc;
    const short* aP1 = aP0 + 16 * CC;
    const short* bP0 = Wqb + (size_t)(nt * 128 + row0) * CC + kc;
    const short* bP1 = bP0 + 16 * CC;
    const int aD0 = wave * 1024, aD1 = aD0 + 512;
    const int bD0 = 4096 + aD0,  bD1 = bD0 + 512;

    const int aoff0 = (wr * 64 + rl) * 32 + rg;
    const int boff0 = 4096 + (wc * 64 + rl) * 32 + rg;

    f32x4 acc[4][4] = {};
    short8 a0[4], b0[4], a1[4], b1[4];

    GEMM_PROLOGUE();
    { const short* bp = &lds[0][0];
#pragma unroll
      for (int i = 0; i < 4; ++i) {
          a0[i] = *(const short8*)(bp + aoff0 + i * 512);
          b0[i] = *(const short8*)(bp + boff0 + i * 512);
      } }

#pragma unroll 1
    for (int it = 0; it < 16; ++it) {
        const int ks0 = it * 2;
        // ---- half 0: MFMA frags[ks0] (set0), fetch frags[ks0+1] -> set1 ----
        if (ks0 == 30) { VMCNT0(); } else { VMCNT4(); }
        SBAR();
        { const short* bp = &lds[(ks0 + 1) & 3][0];
#pragma unroll
          for (int i = 0; i < 4; ++i) {
              a1[i] = *(const short8*)(bp + aoff0 + i * 512);
              b1[i] = *(const short8*)(bp + boff0 + i * 512);
          } }
        if (it < 15) STAGE_NEXT((ks0 + 3) & 3);
        SCHED0();
        __builtin_amdgcn_s_setprio(1);
#pragma unroll
        for (int i = 0; i < 4; ++i)
#pragma unroll
            for (int j = 0; j < 4; ++j)
                acc[i][j] = __builtin_amdgcn_mfma_f32_16x16x32_bf16(a0[i], b0[j], acc[i][j], 0, 0, 0);
        __builtin_amdgcn_s_setprio(0);
        // ---- half 1: MFMA frags[ks0+1] (set1), fetch frags[ks0+2] -> set0 ----
        if (it < 15) {
            VMCNT4(); SBAR();
            { const short* bp = &lds[(ks0 + 2) & 3][0];
#pragma unroll
              for (int i = 0; i < 4; ++i) {
                  a0[i] = *(const short8*)(bp + aoff0 + i * 512);
                  b0[i] = *(const short8*)(bp + boff0 + i * 512);
              } }
            if (it < 14) STAGE_NEXT((ks0 + 4) & 3);
            SCHED0();
        }
        __builtin_amdgcn_s_setprio(1);
#pragma unroll
        for (int i = 0; i < 4; ++i)
#pragma unroll
            for (int j = 0; j < 4; ++j)
                acc[i][j] = __builtin_amdgcn_mfma_f32_16x16x32_bf16(a1[i], b1[j], acc[i][j], 0, 0, 0);
        __builtin_amdgcn_s_setprio(0);
    }

    // ---- fused epilogue: wave wc's 64-col span = one full head ----
    float bias[4], ks[4], kv[4];
#pragma unroll
    for (int j = 0; j < 4; ++j) {
        const int c = nt * 128 + wc * 64 + j * 16 + rl;
        bias[j] = bq[c];
        ks[j]   = ksum[b * CC + c];
        kv[j]   = kvsum[b * CC + c];
    }
#pragma unroll
    for (int i = 0; i < 4; ++i)
#pragma unroll
        for (int j = 0; j < 4; ++j)
#pragma unroll
            for (int r = 0; r < 4; ++r)
                acc[i][j][r] = phi_f(acc[i][j][r] + bias[j]);
#pragma unroll
    for (int i = 0; i < 4; ++i) {
#pragma unroll
        for (int r = 0; r < 4; ++r) {
            float d = acc[i][0][r] * ks[0] + acc[i][1][r] * ks[1]
                    + acc[i][2][r] * ks[2] + acc[i][3][r] * ks[3];
            d += __shfl_xor(d, 1); d += __shfl_xor(d, 2);
            d += __shfl_xor(d, 4); d += __shfl_xor(d, 8);
            const float inv = 0.125f / (d + EPS);
            const int trow = mrow * 128 + wr * 64 + i * 16 + q4 * 4 + r;
#pragma unroll
            for (int j = 0; j < 4; ++j) {
                const int c = nt * 128 + wc * 64 + j * 16 + rl;
                outT[(size_t)trow * CC + c] = f2bf(acc[i][j][r] * kv[j] * inv);
            }
        }
    }
}

// ------- gemm_kv : dual GEMM (k,v) fused phi + t-reduction -> ksum/kvsum -------
// grid 1536 = 96 mrow x 16 cb; B-LDS rows 0-63 = Wk, 64-127 = Wv
__global__ __launch_bounds__(256, 2)
void gemm_kv_kernel(const short* __restrict__ xaT, const short* __restrict__ Wkb,
                    const short* __restrict__ Wvb, const float* __restrict__ bv,
                    float* __restrict__ ksum, float* __restrict__ kvsum)
{
    __shared__ short lds[4][8192];
    const int f    = blockIdx.x;
    const int L    = (f & 7) * 192 + (f >> 3);
    const int cb   = L % 16;
    const int mrow = L / 16;
    const int b    = mrow / 12;
    const int tid  = threadIdx.x;
    const int wave = tid >> 6, lane = tid & 63;
    const int wr = wave >> 1;
    const int wc = wave & 1;
    const int rl = lane & 15;
    const int q4 = lane >> 4;
    const int rg = (q4 ^ ((rl >> 1) & 3)) << 3;

    const int lrow = lane >> 2;
    const int kc   = ((lane & 3) ^ ((lrow >> 1) & 3)) << 3;
    const int row0 = wave * 32 + lrow;
    const short* aP0 = xaT + (size_t)(mrow * 128 + row0) * CC + kc;
    const short* aP1 = aP0 + 16 * CC;
    const short* bPanel = (wave < 2)
        ? Wkb + (size_t)cb * 64 * CC
        : Wvb + (size_t)cb * 64 * CC - (size_t)64 * CC;
    const short* bP0 = bPanel + (size_t)row0 * CC + kc;
    const short* bP1 = bP0 + 16 * CC;
    const int aD0 = wave * 1024, aD1 = aD0 + 512;
    const int bD0 = 4096 + aD0,  bD1 = bD0 + 512;

    const int aoff0 = (wr * 64 + rl) * 32 + rg;
    const int boffK = 4096 + (wc * 32 + rl) * 32 + rg;   // + jj*512
    const int boffV = boffK + 2048;

    f32x4 acc[4][4] = {};   // [i][0..1]=k, [i][2..3]=v (same cols)
    short8 a0[4], b0[4], a1[4], b1[4];   // b[0..1]=K, b[2..3]=V

    GEMM_PROLOGUE();
    { const short* bp = &lds[0][0];
#pragma unroll
      for (int i = 0; i < 4; ++i)
          a0[i] = *(const short8*)(bp + aoff0 + i * 512);
#pragma unroll
      for (int j = 0; j < 2; ++j) {
          b0[j]     = *(const short8*)(bp + boffK + j * 512);
          b0[j + 2] = *(const short8*)(bp + boffV + j * 512);
      } }

#pragma unroll 1
    for (int it = 0; it < 16; ++it) {
        const int ks0 = it * 2;
        if (ks0 == 30) { VMCNT0(); } else { VMCNT4(); }
        SBAR();
        { const short* bp = &lds[(ks0 + 1) & 3][0];
#pragma unroll
          for (int i = 0; i < 4; ++i)
              a1[i] = *(const short8*)(bp + aoff0 + i * 512);
#pragma unroll
          for (int j = 0; j < 2; ++j) {
              b1[j]     = *(const short8*)(bp + boffK + j * 512);
              b1[j + 2] = *(const short8*)(bp + boffV + j * 512);
          } }
        if (it < 15) STAGE_NEXT((ks0 + 3) & 3);
        SCHED0();
        __builtin_amdgcn_s_setprio(1);
#pragma unroll
        for (int i = 0; i < 4; ++i)
#pragma unroll
            for (int j = 0; j < 4; ++j)
                acc[i][j] = __builtin_amdgcn_mfma_f32_16x16x32_bf16(a0[i], b0[j], acc[i][j], 0, 0, 0);
        __builtin_amdgcn_s_setprio(0);
        if (it < 15) {
            VMCNT4(); SBAR();
            { const short* bp = &lds[(ks0 + 2) & 3][0];
#pragma unroll
              for (int i = 0; i < 4; ++i)
                  a0[i] = *(const short8*)(bp + aoff0 + i * 512);
#pragma unroll
              for (int j = 0; j < 2; ++j) {
                  b0[j]     = *(const short8*)(bp + boffK + j * 512);
                  b0[j + 2] = *(const short8*)(bp + boffV + j * 512);
              } }
            if (it < 14) STAGE_NEXT((ks0 + 4) & 3);
            SCHED0();
        }
        __builtin_amdgcn_s_setprio(1);
#pragma unroll
        for (int i = 0; i < 4; ++i)
#pragma unroll
            for (int j = 0; j < 4; ++j)
                acc[i][j] = __builtin_amdgcn_mfma_f32_16x16x32_bf16(a1[i], b1[j], acc[i][j], 0, 0, 0);
        __builtin_amdgcn_s_setprio(0);
    }

    const int tq0 = (mrow % 12) * 128 + wr * 64 + q4 * 4;
#pragma unroll
    for (int jj = 0; jj < 2; ++jj) {
        const int c = cb * 64 + wc * 32 + jj * 16 + rl;
        const float bvc = bv[c];
        float sk = 0.f, skv = 0.f;
#pragma unroll
        for (int i = 0; i < 4; ++i) {
#pragma unroll
            for (int r = 0; r < 4; ++r) {
                if (tq0 + i * 16 + r < TQ) {
                    float pk = phi_f(acc[i][jj][r]);
                    float vv = acc[i][jj + 2][r] + bvc;
                    sk  += pk;
                    skv += pk * vv;
                }
            }
        }
        sk  += __shfl_xor(sk, 16);  sk  += __shfl_xor(sk, 32);
        skv += __shfl_xor(skv, 16); skv += __shfl_xor(skv, 32);
        if (q4 == 0) {
            atomicAdd(&ksum[b * CC + c], sk);
            atomicAdd(&kvsum[b * CC + c], skv);
        }
    }
}

// ---------------- gemm_o : y[b][c][t] = Wo out + bo, m=c n=t, mask t<TQ ----------------
// grid 768 = (8 b x 12 tt) x 8 ct; XCD-swizzled, ct fastest
__global__ __launch_bounds__(256, 2)
void gemm_o_kernel(const short* __restrict__ Wob, const short* __restrict__ outT,
                   const float* __restrict__ bo, float* __restrict__ y)
{
    __shared__ short lds[4][8192];
    const int f    = blockIdx.x;
    const int L    = (f & 7) * 96 + (f >> 3);
    const int ct   = L % 8;
    const int rest = L / 8;
    const int b    = rest / 12;
    const int tt   = rest % 12;
    const int tid  = threadIdx.x;
    const int wave = tid >> 6, lane = tid & 63;
    const int wr = wave >> 1;
    const int wc = wave & 1;
    const int rl = lane & 15;
    const int q4 = lane >> 4;
    const int rg = (q4 ^ ((rl >> 1) & 3)) << 3;

    const int lrow = lane >> 2;
    const int kc   = ((lane & 3) ^ ((lrow >> 1) & 3)) << 3;
    const int row0 = wave * 32 + lrow;
    const short* aP0 = Wob  + (size_t)(ct * 128 + row0) * CC + kc;
    const short* aP1 = aP0 + 16 * CC;
    const short* bP0 = outT + (size_t)(rest * 128 + row0) * CC + kc;
    const short* bP1 = bP0 + 16 * CC;
    const int aD0 = wave * 1024, aD1 = aD0 + 512;
    const int bD0 = 4096 + aD0,  bD1 = bD0 + 512;

    const int aoff0 = (wr * 64 + rl) * 32 + rg;
    const int boff0 = 4096 + (wc * 64 + rl) * 32 + rg;

    f32x4 acc[4][4] = {};
    short8 a0[4], b0[4], a1[4], b1[4];

    GEMM_PROLOGUE();
    { const short* bp = &lds[0][0];
#pragma unroll
      for (int i = 0; i < 4; ++i) {
          a0[i] = *(const short8*)(bp + aoff0 + i * 512);
          b0[i] = *(const short8*)(bp + boff0 + i * 512);
      } }

#pragma unroll 1
    for (int it = 0; it < 16; ++it) {
        const int ks0 = it * 2;
        if (ks0 == 30) { VMCNT0(); } else { VMCNT4(); }
        SBAR();
        { const short* bp = &lds[(ks0 + 1) & 3][0];
#pragma unroll
          for (int i = 0; i < 4; ++i) {
              a1[i] = *(const short8*)(bp + aoff0 + i * 512);
              b1[i] = *(const short8*)(bp + boff0 + i * 512);
          } }
        if (it < 15) STAGE_NEXT((ks0 + 3) & 3);
        SCHED0();
        __builtin_amdgcn_s_setprio(1);
#pragma unroll
        for (int i = 0; i < 4; ++i)
#pragma unroll
            for (int j = 0; j < 4; ++j)
                acc[i][j] = __builtin_amdgcn_mfma_f32_16x16x32_bf16(a0[i], b0[j], acc[i][j], 0, 0, 0);
        __builtin_amdgcn_s_setprio(0);
        if (it < 15) {
            VMCNT4(); SBAR();
            { const short* bp = &lds[(ks0 + 2) & 3][0];
#pragma unroll
              for (int i = 0; i < 4; ++i) {
                  a0[i] = *(const short8*)(bp + aoff0 + i * 512);
                  b0[i] = *(const short8*)(bp + boff0 + i * 512);
              } }
            if (it < 14) STAGE_NEXT((ks0 + 4) & 3);
            SCHED0();
        }
        __builtin_amdgcn_s_setprio(1);
#pragma unroll
        for (int i = 0; i < 4; ++i)
#pragma unroll
            for (int j = 0; j < 4; ++j)
                acc[i][j] = __builtin_amdgcn_mfma_f32_16x16x32_bf16(a1[i], b1[j], acc[i][j], 0, 0, 0);
        __builtin_amdgcn_s_setprio(0);
    }

#pragma unroll
    for (int j = 0; j < 4; ++j) {
        const int t = tt * 128 + wc * 64 + j * 16 + rl;
        if (t >= TQ) continue;
#pragma unroll
        for (int i = 0; i < 4; ++i) {
            const int cbase = ct * 128 + wr * 64 + i * 16 + q4 * 4;
#pragma unroll
            for (int r = 0; r < 4; ++r) {
                const int c = cbase + r;
                y[((size_t)b * CC + c) * TQ + t] = acc[i][j][r] + bo[c];
            }
        }
    }
}

extern "C" void kernel_launch(void* const* d_in, const int* in_sizes, int n_in,
                              void* d_out, int out_size, void* d_ws, size_t ws_size,
                              hipStream_t stream)
{
    (void)in_sizes; (void)n_in; (void)out_size; (void)ws_size;
    const float* x  = (const float*)d_in[0];
    const float* xa = (const float*)d_in[1];
    const float* Wq = (const float*)d_in[2];
    const float* bq = (const float*)d_in[3];
    const float* Wk = (const float*)d_in[4];
    const float* Wv = (const float*)d_in[5];
    const float* bv = (const float*)d_in[6];
    const float* Wo = (const float*)d_in[7];
    const float* bo = (const float*)d_in[8];
    float* y = (float*)d_out;
    char* ws = (char*)d_ws;

    short* xT    = (short*)(ws + XT_OFF);
    short* xaT   = (short*)(ws + XAT_OFF);
    short* outT  = (short*)(ws + OUT_OFF);
    short* Wqb   = (short*)(ws + WB_OFF);
    short* Wkb   = Wqb + (size_t)CC * CC;
    short* Wvb   = Wkb + (size_t)CC * CC;
    short* Wob   = Wvb + (size_t)CC * CC;
    float* ksum  = (float*)(ws + KSUM_OFF);
    float* kvsum = (float*)(ws + KVSUM_OFF);

    prep_kernel<<<dim3(1024 + 6144), 256, 0, stream>>>(x, xa, Wq, Wk, Wv, Wo,
                                                       Wqb, Wkb, Wvb, Wob, xT, xaT, ksum);
    gemm_kv_kernel<<<dim3(1536), 256, 0, stream>>>(xaT, Wkb, Wvb, bv, ksum, kvsum);
    gemm_q_out_kernel<<<dim3(768), 256, 0, stream>>>(xT, Wqb, bq, ksum, kvsum, outT);
    gemm_o_kernel<<<dim3(768), 256, 0, stream>>>(Wob, outT, bo, y);
}